// Round 3
// baseline (1815.147 us; speedup 1.0000x reference)
//
#include <hip/hip_runtime.h>
#include <cstdint>
#include <cstddef>

// I/O fp32; intermediates bf16; math fp32.
typedef __bf16 bf16x8 __attribute__((ext_vector_type(8)));
typedef float  f32x4  __attribute__((ext_vector_type(4)));

__device__ __forceinline__ float bf2f(unsigned short u) {
  union { unsigned int u; float f; } v; v.u = ((unsigned int)u) << 16; return v.f;
}
__device__ __forceinline__ unsigned short f2bf(float f) {
  union { float f; unsigned int u; } v; v.f = f;
  return (unsigned short)((v.u + 0x7fffu + ((v.u >> 16) & 1u)) >> 16);
}
__device__ __forceinline__ void g2lds16(const void* g, void* l) {
  __builtin_amdgcn_global_load_lds((__attribute__((address_space(1))) void*)g,
                                   (__attribute__((address_space(3))) void*)l,
                                   16, 0, 0);
}

// ---------- GEMM: C[M,N](bf16) = A[M,K](bf16) * BT[N,K](bf16)^T + bias(fp32) ----------
// EPI: 0 = +bias, 1 = +bias then gelu(tanh-approx)
template<int EPI>
__global__ __launch_bounds__(256) void gemm_bt(
    const unsigned short* __restrict__ A, const unsigned short* __restrict__ BT,
    const float* __restrict__ bias, unsigned short* __restrict__ C,
    int M, int N, int K)
{
  __shared__ __align__(16) unsigned short ldsA[128 * 32];
  __shared__ __align__(16) unsigned short ldsB[128 * 32];
  const int tid  = threadIdx.x;
  const int wave = tid >> 6;
  const int lane = tid & 63;
  const int bm = blockIdx.y, bn = blockIdx.x;
  const int lm = lane & 15, quad = lane >> 4;
  const int wm = (wave >> 1) * 64, wn = (wave & 1) * 64;

  f32x4 acc[4][4];
#pragma unroll
  for (int i = 0; i < 4; i++)
#pragma unroll
    for (int j = 0; j < 4; j++) acc[i][j] = {0.f, 0.f, 0.f, 0.f};

  const int sr = lane >> 2;          // row within this wave's 16-row slab
  const int sc = (lane & 3) * 8;     // k-offset of this lane's 16B chunk
  const size_t rowA0 = (size_t)(bm * 128 + wave * 16 + sr);
  const size_t rowB0 = (size_t)(bn * 128 + wave * 16 + sr);
  const unsigned short* pA0 = A  + rowA0 * K + sc;
  const unsigned short* pA1 = A  + (rowA0 + 64) * K + sc;
  const unsigned short* pB0 = BT + rowB0 * K + sc;
  const unsigned short* pB1 = BT + (rowB0 + 64) * K + sc;
  unsigned short* lA0 = &ldsA[(wave * 16) * 32];
  unsigned short* lA1 = &ldsA[(64 + wave * 16) * 32];
  unsigned short* lB0 = &ldsB[(wave * 16) * 32];
  unsigned short* lB1 = &ldsB[(64 + wave * 16) * 32];

  for (int k0 = 0; k0 < K; k0 += 32) {
    g2lds16(pA0 + k0, lA0);
    g2lds16(pA1 + k0, lA1);
    g2lds16(pB0 + k0, lB0);
    g2lds16(pB1 + k0, lB1);
    __syncthreads();
    bf16x8 af[4], bfr[4];
#pragma unroll
    for (int i = 0; i < 4; i++)
      af[i] = *reinterpret_cast<const bf16x8*>(&ldsA[(wm + i * 16 + lm) * 32 + quad * 8]);
#pragma unroll
    for (int j = 0; j < 4; j++)
      bfr[j] = *reinterpret_cast<const bf16x8*>(&ldsB[(wn + j * 16 + lm) * 32 + quad * 8]);
#pragma unroll
    for (int i = 0; i < 4; i++)
#pragma unroll
      for (int j = 0; j < 4; j++)
        acc[i][j] = __builtin_amdgcn_mfma_f32_16x16x32_bf16(af[i], bfr[j], acc[i][j], 0, 0, 0);
    __syncthreads();
  }

#pragma unroll
  for (int i = 0; i < 4; i++) {
#pragma unroll
    for (int j = 0; j < 4; j++) {
#pragma unroll
      for (int r = 0; r < 4; r++) {
        int row = bm * 128 + wm + i * 16 + quad * 4 + r;
        int col = bn * 128 + wn + j * 16 + lm;
        float v = acc[i][j][r];
        if (bias) v += bias[col];
        if (EPI == 1) {
          float xx = v;
          float u = 1.5957691216057308f * (xx + 0.044715f * xx * xx * xx);
          v = xx / (1.f + __expf(-u));   // x*sigmoid(2z) == 0.5x(1+tanh z)
        }
        C[(size_t)row * N + col] = f2bf(v);
      }
    }
  }
}

// ---------- weight transpose + cast: W[K,N] fp32 -> WT[N,K] bf16 ----------
__global__ __launch_bounds__(256) void transpose_cast(
    const float* __restrict__ W, unsigned short* __restrict__ WT, int K, int N)
{
  __shared__ float t[32][33];
  int bx = blockIdx.x, by = blockIdx.y;           // bx over N/32, by over K/32
  int tx = threadIdx.x & 31, ty = threadIdx.x >> 5;
#pragma unroll
  for (int j = 0; j < 4; j++)
    t[ty + j * 8][tx] = W[(size_t)(by * 32 + ty + j * 8) * N + bx * 32 + tx];
  __syncthreads();
#pragma unroll
  for (int j = 0; j < 4; j++)
    WT[(size_t)(bx * 32 + ty + j * 8) * K + by * 32 + tx] = f2bf(t[tx][ty + j * 8]);
}

// ---------- shift + window partition + cast: x (B,4096,512) fp32 -> xw (65536,512) bf16 ----------
__global__ __launch_bounds__(256) void shift_part(
    const float* __restrict__ x, unsigned short* __restrict__ xw)
{
  int t = blockIdx.x * 256 + threadIdx.x;   // 65536 rows * 128 chunks of 4
  int row = t >> 7;
  int c = (t & 127) * 4;
  int b = row >> 12, rw_ = row & 4095;
  int wi = rw_ >> 6, p = rw_ & 63;
  int hh = (((wi >> 3) * 8 + (p >> 3)) + 4) & 63;
  int ww = (((wi & 7) * 8 + (p & 7)) + 4) & 63;
  const float4 v = *(const float4*)&x[(((size_t)b * 4096) + hh * 64 + ww) * 512 + c];
  ushort4 o;
  o.x = f2bf(v.x); o.y = f2bf(v.y); o.z = f2bf(v.z); o.w = f2bf(v.w);
  *(ushort4*)&xw[(size_t)row * 512 + c] = o;
}

// ---------- CPB table: tbl[225][16] fp32 ----------
__device__ __forceinline__ float relsc(int v) {
  float a = fabsf((float)v) * (8.0f / 7.0f);
  float r = log2f(a + 1.f) * (1.f / 3.f);
  return v < 0 ? -r : r;
}
__global__ __launch_bounds__(512) void cpb_kernel(
    const float* __restrict__ w1, const float* __restrict__ b1,
    const float* __restrict__ w2, const float* __restrict__ b2, float* __restrict__ tbl)
{
  __shared__ float hid[512];
  int p = blockIdx.x;            // p = (dr+7)*15 + (dc+7)
  int i = p / 15, j = p % 15;
  float fr = relsc(i - 7);       // row-delta feature (channel 1)
  float fc = relsc(j - 7);       // col-delta feature (channel 0)
  int t = threadIdx.x;
  float hv = fc * w1[t] + fr * w1[512 + t] + b1[t];
  hid[t] = fmaxf(hv, 0.f);
  __syncthreads();
  if (t < 16) {
    float s = b2[t];
    for (int u = 0; u < 512; u++) s += hid[u] * w2[u * 16 + t];
    tbl[p * 16 + t] = s;
  }
}

// ---------- attention: one block per (window, head) ----------
__global__ __launch_bounds__(256) void attn_kernel(
    const unsigned short* __restrict__ Qm, const unsigned short* __restrict__ Km,
    const unsigned short* __restrict__ Vm, const float* __restrict__ tau,
    const float* __restrict__ tbl, unsigned short* __restrict__ Om)
{
  __shared__ float Qs[64][32];
  __shared__ float Ks[64][32];
  __shared__ float Vs[64][32];
  __shared__ float S[64][64];
  __shared__ float qn[64], kn[64];
  __shared__ float tblh[225];
  const int tid = threadIdx.x;
  const int w = blockIdx.x >> 4, h = blockIdx.x & 15;
  const int wi = w & 63, wr = wi >> 3, wc = wi & 7;
  const size_t base = ((size_t)w * 64) * 512 + h * 32;

  for (int e = tid; e < 2048; e += 256) {
    int p = e >> 5, d = e & 31;
    size_t a = base + (size_t)p * 512 + d;
    Qs[p][d] = bf2f(Qm[a]); Ks[p][d] = bf2f(Km[a]); Vs[p][d] = bf2f(Vm[a]);
  }
  if (tid < 225) tblh[tid] = tbl[tid * 16 + h];
  __syncthreads();
  if (tid < 64) {
    float s = 0;
    for (int d = 0; d < 32; d++) s += Qs[tid][d] * Qs[tid][d];
    qn[tid] = sqrtf(s);
  } else if (tid < 128) {
    int q = tid - 64; float s = 0;
    for (int d = 0; d < 32; d++) s += Ks[q][d] * Ks[q][d];
    kn[q] = sqrtf(s);
  }
  __syncthreads();
  const float scale = fmaxf(tau[h] + 2.302585092994046f, 0.01f);
  for (int e = tid; e < 4096; e += 256) {
    int p = e >> 6, q = e & 63;
    float dot = 0;
    for (int d = 0; d < 32; d++) dot += Qs[p][d] * Ks[q][d];
    float denom = fmaxf(qn[p] * kn[q], 1e-6f);
    int dr = (p >> 3) - (q >> 3) + 7, dc = (p & 7) - (q & 7) + 7;
    float bv = tblh[dr * 15 + dc];
    bv = 16.f / (1.f + __expf(-bv));
    int rp = wr * 8 + (p >> 3), cp = wc * 8 + (p & 7);
    int rq = wr * 8 + (q >> 3), cq = wc * 8 + (q & 7);
    int codep = (rp < 56 ? 0 : (rp < 60 ? 1 : 2)) * 3 + (cp < 56 ? 0 : (cp < 60 ? 1 : 2));
    int codeq = (rq < 56 ? 0 : (rq < 60 ? 1 : 2)) * 3 + (cq < 56 ? 0 : (cq < 60 ? 1 : 2));
    float mask = (codep == codeq) ? 0.f : -100.f;
    S[p][q] = dot / denom * scale + bv + mask;
  }
  __syncthreads();
  if (tid < 64) {
    int p = tid; float m = -1e30f;
    for (int q = 0; q < 64; q++) m = fmaxf(m, S[p][q]);
    float s = 0;
    for (int q = 0; q < 64; q++) { float e = __expf(S[p][q] - m); S[p][q] = e; s += e; }
    float inv = 1.f / s;
    for (int q = 0; q < 64; q++) S[p][q] *= inv;
  }
  __syncthreads();
  for (int e = tid; e < 2048; e += 256) {
    int p = e >> 5, d = e & 31;
    float a = 0;
    for (int q = 0; q < 64; q++) a += S[p][q] * Vs[q][d];
    Om[base + (size_t)p * 512 + d] = f2bf(a);
  }
}

// ---------- LN1: un-shift/window-reverse gather + layernorm + residual -> x1 bf16 ----------
__global__ __launch_bounds__(256) void ln1_kernel(
    const float* __restrict__ x, const unsigned short* __restrict__ proj,
    const float* __restrict__ g, const float* __restrict__ b,
    unsigned short* __restrict__ x1b)
{
  __shared__ float r1[4], r2[4], stats[2];
  int tkn = blockIdx.x;
  int bb = tkn >> 12, s = tkn & 4095;
  int h_ = s >> 6, w_ = s & 63;
  int r = (h_ + 60) & 63, cc = (w_ + 60) & 63;
  int wi = (r >> 3) * 8 + (cc >> 3);
  int p = (r & 7) * 8 + (cc & 7);
  size_t src = ((size_t)bb * 4096 + wi * 64 + p) * 512;
  int c = threadIdx.x * 2;
  unsigned int pv = *(const unsigned int*)&proj[src + c];
  float v0 = bf2f((unsigned short)(pv & 0xffff)), v1 = bf2f((unsigned short)(pv >> 16));
  float ls = v0 + v1, lq = v0 * v0 + v1 * v1;
  for (int off = 32; off > 0; off >>= 1) {
    ls += __shfl_down(ls, off, 64);
    lq += __shfl_down(lq, off, 64);
  }
  int wv = threadIdx.x >> 6, ln = threadIdx.x & 63;
  if (ln == 0) { r1[wv] = ls; r2[wv] = lq; }
  __syncthreads();
  if (threadIdx.x == 0) {
    float S1 = r1[0] + r1[1] + r1[2] + r1[3];
    float S2 = r2[0] + r2[1] + r2[2] + r2[3];
    float mean = S1 * (1.f / 512.f);
    float var = S2 * (1.f / 512.f) - mean * mean;
    stats[0] = mean; stats[1] = rsqrtf(var + 1e-6f);
  }
  __syncthreads();
  float mean = stats[0], rstd = stats[1];
  size_t o = (size_t)tkn * 512 + c;
  float2 xv = *(const float2*)&x[o];
  float y0 = (v0 - mean) * rstd * g[c] + b[c] + xv.x;
  float y1 = (v1 - mean) * rstd * g[c + 1] + b[c + 1] + xv.y;
  unsigned int ov = (unsigned int)f2bf(y0) | ((unsigned int)f2bf(y1) << 16);
  *(unsigned int*)&x1b[o] = ov;
}

// ---------- LN2 + residual -> out fp32 ----------
__global__ __launch_bounds__(256) void ln2_kernel(
    const unsigned short* __restrict__ x1b, const unsigned short* __restrict__ h2,
    const float* __restrict__ g, const float* __restrict__ b,
    float* __restrict__ out)
{
  __shared__ float r1[4], r2[4], stats[2];
  int tkn = blockIdx.x;
  int c = threadIdx.x * 2;
  size_t o = (size_t)tkn * 512 + c;
  unsigned int hv = *(const unsigned int*)&h2[o];
  float v0 = bf2f((unsigned short)(hv & 0xffff)), v1 = bf2f((unsigned short)(hv >> 16));
  float ls = v0 + v1, lq = v0 * v0 + v1 * v1;
  for (int off = 32; off > 0; off >>= 1) {
    ls += __shfl_down(ls, off, 64);
    lq += __shfl_down(lq, off, 64);
  }
  int wv = threadIdx.x >> 6, ln = threadIdx.x & 63;
  if (ln == 0) { r1[wv] = ls; r2[wv] = lq; }
  __syncthreads();
  if (threadIdx.x == 0) {
    float S1 = r1[0] + r1[1] + r1[2] + r1[3];
    float S2 = r2[0] + r2[1] + r2[2] + r2[3];
    float mean = S1 * (1.f / 512.f);
    float var = S2 * (1.f / 512.f) - mean * mean;
    stats[0] = mean; stats[1] = rsqrtf(var + 1e-6f);
  }
  __syncthreads();
  float mean = stats[0], rstd = stats[1];
  unsigned int xv = *(const unsigned int*)&x1b[o];
  float x0 = bf2f((unsigned short)(xv & 0xffff)), x1 = bf2f((unsigned short)(xv >> 16));
  float2 ov;
  ov.x = x0 + (v0 - mean) * rstd * g[c] + b[c];
  ov.y = x1 + (v1 - mean) * rstd * g[c + 1] + b[c + 1];
  *(float2*)&out[o] = ov;
}

// ---------- launcher ----------
extern "C" void kernel_launch(void* const* d_in, const int* in_sizes, int n_in,
                              void* d_out, int out_size, void* d_ws, size_t ws_size,
                              hipStream_t stream) {
  const float* x      = (const float*)d_in[0];
  const float* q_w    = (const float*)d_in[1];
  const float* q_b    = (const float*)d_in[2];
  const float* k_w    = (const float*)d_in[3];
  const float* v_w    = (const float*)d_in[4];
  const float* v_b    = (const float*)d_in[5];
  const float* proj_w = (const float*)d_in[6];
  const float* proj_b = (const float*)d_in[7];
  const float* tau    = (const float*)d_in[8];
  const float* cpb_w1 = (const float*)d_in[9];
  const float* cpb_b1 = (const float*)d_in[10];
  const float* cpb_w2 = (const float*)d_in[11];
  const float* cpb_b2 = (const float*)d_in[12];
  const float* n1g    = (const float*)d_in[13];
  const float* n1b    = (const float*)d_in[14];
  const float* n2g    = (const float*)d_in[15];
  const float* n2b    = (const float*)d_in[16];
  const float* mlp_w1 = (const float*)d_in[17];
  const float* mlp_b1 = (const float*)d_in[18];
  const float* mlp_w2 = (const float*)d_in[19];
  const float* mlp_b2 = (const float*)d_in[20];
  float* out = (float*)d_out;
  char* ws = (char*)d_ws;

  // workspace layout (bf16 intermediates), ~326 MiB total:
  //   [0,64)    xw  -> O    (xw dead after QKV GEMMs)
  //   [64,128)  q   -> projb (q dead after attn)
  //   [128,192) k   -> x1b   (k dead after attn)
  //   [192,256) v   -> h2b   (v dead after attn)
  //   [256,320) h chunk (16384 x 2048 bf16, reused 4x)
  //   [320,..)  bf16 weights + cpb table (~6.1 MiB)
  const size_t MB = 1048576;
  unsigned short* xw    = (unsigned short*)(ws + 0 * MB);
  unsigned short* Obuf  = (unsigned short*)(ws + 0 * MB);
  unsigned short* qbuf  = (unsigned short*)(ws + 64 * MB);
  unsigned short* projb = (unsigned short*)(ws + 64 * MB);
  unsigned short* kbuf  = (unsigned short*)(ws + 128 * MB);
  unsigned short* x1b   = (unsigned short*)(ws + 128 * MB);
  unsigned short* vbuf  = (unsigned short*)(ws + 192 * MB);
  unsigned short* h2b   = (unsigned short*)(ws + 192 * MB);
  unsigned short* hbuf  = (unsigned short*)(ws + 256 * MB);
  unsigned short* qwT = (unsigned short*)(ws + 320 * MB);
  unsigned short* kwT = (unsigned short*)(ws + 320 * MB + 524288);
  unsigned short* vwT = (unsigned short*)(ws + 320 * MB + 1048576);
  unsigned short* pwT = (unsigned short*)(ws + 320 * MB + 1572864);
  unsigned short* m1T = (unsigned short*)(ws + 320 * MB + 2097152);
  unsigned short* m2T = (unsigned short*)(ws + 320 * MB + 4194304);
  float* tbl          = (float*)         (ws + 320 * MB + 6291456);

  transpose_cast<<<dim3(16, 16), 256, 0, stream>>>(q_w,    qwT, 512, 512);
  transpose_cast<<<dim3(16, 16), 256, 0, stream>>>(k_w,    kwT, 512, 512);
  transpose_cast<<<dim3(16, 16), 256, 0, stream>>>(v_w,    vwT, 512, 512);
  transpose_cast<<<dim3(16, 16), 256, 0, stream>>>(proj_w, pwT, 512, 512);
  transpose_cast<<<dim3(64, 16), 256, 0, stream>>>(mlp_w1, m1T, 512, 2048);
  transpose_cast<<<dim3(16, 64), 256, 0, stream>>>(mlp_w2, m2T, 2048, 512);
  cpb_kernel<<<225, 512, 0, stream>>>(cpb_w1, cpb_b1, cpb_w2, cpb_b2, tbl);
  shift_part<<<32768, 256, 0, stream>>>(x, xw);
  gemm_bt<0><<<dim3(4, 512), 256, 0, stream>>>(xw, qwT, q_b,     qbuf, 65536, 512, 512);
  gemm_bt<0><<<dim3(4, 512), 256, 0, stream>>>(xw, kwT, nullptr, kbuf, 65536, 512, 512);
  gemm_bt<0><<<dim3(4, 512), 256, 0, stream>>>(xw, vwT, v_b,     vbuf, 65536, 512, 512);
  attn_kernel<<<16384, 256, 0, stream>>>(qbuf, kbuf, vbuf, tau, tbl, Obuf);
  gemm_bt<0><<<dim3(4, 512), 256, 0, stream>>>(Obuf, pwT, proj_b, projb, 65536, 512, 512);
  ln1_kernel<<<65536, 256, 0, stream>>>(x, projb, n1g, n1b, x1b);
  // MLP in 4 row-chunks of 16384 to keep the hidden buffer at 64 MiB
  for (int c4 = 0; c4 < 4; c4++) {
    const unsigned short* a = x1b + (size_t)c4 * 16384 * 512;
    unsigned short* h2p = h2b + (size_t)c4 * 16384 * 512;
    gemm_bt<1><<<dim3(16, 128), 256, 0, stream>>>(a, m1T, mlp_b1, hbuf, 16384, 2048, 512);
    gemm_bt<0><<<dim3(4, 128), 256, 0, stream>>>(hbuf, m2T, mlp_b2, h2p, 16384, 512, 2048);
  }
  ln2_kernel<<<65536, 256, 0, stream>>>(x1b, h2b, n2g, n2b, out);
}

// Round 4
// 1487.072 us; speedup vs baseline: 1.2206x; 1.2206x over previous
//
#include <hip/hip_runtime.h>
#include <cstdint>
#include <cstddef>

// I/O fp32; intermediates bf16; math fp32.
typedef __bf16 bf16x8 __attribute__((ext_vector_type(8)));
typedef float  f32x4  __attribute__((ext_vector_type(4)));

__device__ __forceinline__ float bf2f(unsigned short u) {
  union { unsigned int u; float f; } v; v.u = ((unsigned int)u) << 16; return v.f;
}
__device__ __forceinline__ unsigned short f2bf(float f) {
  union { float f; unsigned int u; } v; v.f = f;
  return (unsigned short)((v.u + 0x7fffu + ((v.u >> 16) & 1u)) >> 16);
}
__device__ __forceinline__ void g2lds16(const void* g, void* l) {
  __builtin_amdgcn_global_load_lds((__attribute__((address_space(1))) void*)g,
                                   (__attribute__((address_space(3))) void*)l,
                                   16, 0, 0);
}

// ---------- GEMM: C[M,N](bf16) = A[M,K](bf16) * BT[N,K](bf16)^T + bias(fp32) ----------
// EPI: 0 = +bias, 1 = +bias then gelu(tanh-approx)
template<int EPI>
__global__ __launch_bounds__(256) void gemm_bt(
    const unsigned short* __restrict__ A, const unsigned short* __restrict__ BT,
    const float* __restrict__ bias, unsigned short* __restrict__ C,
    int M, int N, int K)
{
  __shared__ __align__(16) unsigned short ldsA[128 * 32];
  __shared__ __align__(16) unsigned short ldsB[128 * 32];
  const int tid  = threadIdx.x;
  const int wave = tid >> 6;
  const int lane = tid & 63;
  const int bm = blockIdx.y, bn = blockIdx.x;
  const int lm = lane & 15, quad = lane >> 4;
  const int wm = (wave >> 1) * 64, wn = (wave & 1) * 64;

  f32x4 acc[4][4];
#pragma unroll
  for (int i = 0; i < 4; i++)
#pragma unroll
    for (int j = 0; j < 4; j++) acc[i][j] = {0.f, 0.f, 0.f, 0.f};

  const int sr = lane >> 2;
  const int sc = (lane & 3) * 8;
  const size_t rowA0 = (size_t)(bm * 128 + wave * 16 + sr);
  const size_t rowB0 = (size_t)(bn * 128 + wave * 16 + sr);
  const unsigned short* pA0 = A  + rowA0 * K + sc;
  const unsigned short* pA1 = A  + (rowA0 + 64) * K + sc;
  const unsigned short* pB0 = BT + rowB0 * K + sc;
  const unsigned short* pB1 = BT + (rowB0 + 64) * K + sc;
  unsigned short* lA0 = &ldsA[(wave * 16) * 32];
  unsigned short* lA1 = &ldsA[(64 + wave * 16) * 32];
  unsigned short* lB0 = &ldsB[(wave * 16) * 32];
  unsigned short* lB1 = &ldsB[(64 + wave * 16) * 32];

  for (int k0 = 0; k0 < K; k0 += 32) {
    g2lds16(pA0 + k0, lA0);
    g2lds16(pA1 + k0, lA1);
    g2lds16(pB0 + k0, lB0);
    g2lds16(pB1 + k0, lB1);
    __syncthreads();
    bf16x8 af[4], bfr[4];
#pragma unroll
    for (int i = 0; i < 4; i++)
      af[i] = *reinterpret_cast<const bf16x8*>(&ldsA[(wm + i * 16 + lm) * 32 + quad * 8]);
#pragma unroll
    for (int j = 0; j < 4; j++)
      bfr[j] = *reinterpret_cast<const bf16x8*>(&ldsB[(wn + j * 16 + lm) * 32 + quad * 8]);
#pragma unroll
    for (int i = 0; i < 4; i++)
#pragma unroll
      for (int j = 0; j < 4; j++)
        acc[i][j] = __builtin_amdgcn_mfma_f32_16x16x32_bf16(af[i], bfr[j], acc[i][j], 0, 0, 0);
    __syncthreads();
  }

#pragma unroll
  for (int i = 0; i < 4; i++) {
#pragma unroll
    for (int j = 0; j < 4; j++) {
#pragma unroll
      for (int r = 0; r < 4; r++) {
        int row = bm * 128 + wm + i * 16 + quad * 4 + r;
        int col = bn * 128 + wn + j * 16 + lm;
        float v = acc[i][j][r];
        if (bias) v += bias[col];
        if (EPI == 1) {
          float xx = v;
          float u = 1.5957691216057308f * (xx + 0.044715f * xx * xx * xx);
          v = xx / (1.f + __expf(-u));
        }
        C[(size_t)row * N + col] = f2bf(v);
      }
    }
  }
}

// ---------- weight transpose + cast: W[K,N] fp32 -> WT[N,K] bf16 ----------
__global__ __launch_bounds__(256) void transpose_cast(
    const float* __restrict__ W, unsigned short* __restrict__ WT, int K, int N)
{
  __shared__ float t[32][33];
  int bx = blockIdx.x, by = blockIdx.y;
  int tx = threadIdx.x & 31, ty = threadIdx.x >> 5;
#pragma unroll
  for (int j = 0; j < 4; j++)
    t[ty + j * 8][tx] = W[(size_t)(by * 32 + ty + j * 8) * N + bx * 32 + tx];
  __syncthreads();
#pragma unroll
  for (int j = 0; j < 4; j++)
    WT[(size_t)(bx * 32 + ty + j * 8) * K + by * 32 + tx] = f2bf(t[tx][ty + j * 8]);
}

// ---------- shift + window partition + cast ----------
__global__ __launch_bounds__(256) void shift_part(
    const float* __restrict__ x, unsigned short* __restrict__ xw)
{
  int t = blockIdx.x * 256 + threadIdx.x;
  int row = t >> 7;
  int c = (t & 127) * 4;
  int b = row >> 12, rw_ = row & 4095;
  int wi = rw_ >> 6, p = rw_ & 63;
  int hh = (((wi >> 3) * 8 + (p >> 3)) + 4) & 63;
  int ww = (((wi & 7) * 8 + (p & 7)) + 4) & 63;
  const float4 v = *(const float4*)&x[(((size_t)b * 4096) + hh * 64 + ww) * 512 + c];
  ushort4 o;
  o.x = f2bf(v.x); o.y = f2bf(v.y); o.z = f2bf(v.z); o.w = f2bf(v.w);
  *(ushort4*)&xw[(size_t)row * 512 + c] = o;
}

// ---------- CPB table: tbl[225][16] fp32 ----------
__device__ __forceinline__ float relsc(int v) {
  float a = fabsf((float)v) * (8.0f / 7.0f);
  float r = log2f(a + 1.f) * (1.f / 3.f);
  return v < 0 ? -r : r;
}
__global__ __launch_bounds__(512) void cpb_kernel(
    const float* __restrict__ w1, const float* __restrict__ b1,
    const float* __restrict__ w2, const float* __restrict__ b2, float* __restrict__ tbl)
{
  __shared__ float hid[512];
  int p = blockIdx.x;
  int i = p / 15, j = p % 15;
  float fr = relsc(i - 7);
  float fc = relsc(j - 7);
  int t = threadIdx.x;
  float hv = fc * w1[t] + fr * w1[512 + t] + b1[t];
  hid[t] = fmaxf(hv, 0.f);
  __syncthreads();
  if (t < 16) {
    float s = b2[t];
    for (int u = 0; u < 512; u++) s += hid[u] * w2[u * 16 + t];
    tbl[p * 16 + t] = s;
  }
}

// ---------- MFMA attention: one block per window, 4 waves, loop 16 heads ----------
// Wave `wave` owns query strip rows [wave*16, wave*16+16).
// QK^T: A=Q strip (1 frag), B=K tiles (4 frags) -> 4 mfma -> S strip in C-layout.
// Softmax in registers (C-layout: col=lane&15, row=quad*4+reg), 16-lane shfl reduce.
// P -> LDS (A-layout readable), V^T in LDS -> PV: 2x2 mfma -> O strip.
__global__ __launch_bounds__(256) void attn_mfma(
    const unsigned short* __restrict__ Qm, const unsigned short* __restrict__ Km,
    const unsigned short* __restrict__ Vm, const float* __restrict__ tau,
    const float* __restrict__ tbl, unsigned short* __restrict__ Om)
{
  __shared__ __align__(16) unsigned short Qs[64 * 32];   // stride 32 (64B rows)
  __shared__ __align__(16) unsigned short Ks[64 * 32];
  __shared__ __align__(16) unsigned short VT[32 * 72];   // V^T, stride 72 (144B rows)
  __shared__ __align__(16) unsigned short Pb[64 * 72];   // P, stride 72; also stages V rows
  __shared__ float qn[64], kn[64];
  __shared__ float tblh[225];
  __shared__ int scode[64];

  const int tid = threadIdx.x;
  const int wave = tid >> 6, lane = tid & 63;
  const int lm = lane & 15, quad = lane >> 4;
  const int w = blockIdx.x;                 // 0..1023
  const int wi = w & 63, wr = wi >> 3, wc = wi & 7;
  const size_t wbase = (size_t)w * 64 * 512;

  if (tid < 64) {
    int p = tid;
    int rp = wr * 8 + (p >> 3), cp = wc * 8 + (p & 7);
    scode[p] = (rp < 56 ? 0 : (rp < 60 ? 1 : 2)) * 3 + (cp < 56 ? 0 : (cp < 60 ? 1 : 2));
  }

  // staging addresses: per wave, 64 lanes x 16B = 16 rows of a 64x32-bf16 tile
  const int srow = wave * 16 + (lane >> 2);       // row this lane stages
  const int scol = (lane & 3) * 8;                // element offset
  unsigned short* qdst = &Qs[wave * 16 * 32];
  unsigned short* kdst = &Ks[wave * 16 * 32];
  unsigned short* vdst = &Pb[wave * 16 * 32];     // V rows staged into Pb area

  for (int h = 0; h < 16; h++) {
    const size_t gsrc = wbase + (size_t)srow * 512 + h * 32 + scol;
    g2lds16(Qm + gsrc, qdst);
    g2lds16(Km + gsrc, kdst);
    g2lds16(Vm + gsrc, vdst);
    for (int e = tid; e < 225; e += 256) tblh[e] = tbl[e * 16 + h];
    __syncthreads();   // staging complete

    // norms (from the same bf16 values MFMA will consume)
    if (tid < 64) {
      float s = 0;
#pragma unroll
      for (int d = 0; d < 32; d++) { float q_ = bf2f(Qs[tid * 32 + d]); s += q_ * q_; }
      qn[tid] = sqrtf(s);
    } else if (tid < 128) {
      int q = tid - 64; float s = 0;
#pragma unroll
      for (int d = 0; d < 32; d++) { float k_ = bf2f(Ks[q * 32 + d]); s += k_ * k_; }
      kn[q] = sqrtf(s);
    }
    // V^T build: VT[d][q] = Vrow[q][d]
    for (int e = tid; e < 2048; e += 256) {
      int d = e >> 6, q = e & 63;
      VT[d * 72 + q] = Pb[q * 32 + d];
    }
    __syncthreads();   // VT, norms ready; Pb(Vrows) dead

    // ---- QK^T for this wave's strip ----
    bf16x8 af = *reinterpret_cast<const bf16x8*>(&Qs[(wave * 16 + lm) * 32 + quad * 8]);
    f32x4 accS[4];
#pragma unroll
    for (int ni = 0; ni < 4; ni++) {
      bf16x8 bfr = *reinterpret_cast<const bf16x8*>(&Ks[(ni * 16 + lm) * 32 + quad * 8]);
      f32x4 z = {0.f, 0.f, 0.f, 0.f};
      accS[ni] = __builtin_amdgcn_mfma_f32_16x16x32_bf16(af, bfr, z, 0, 0, 0);
    }

    // ---- epilogue + softmax (C-layout) ----
    const float scale = fmaxf(tau[h] + 2.302585092994046f, 0.01f);
#pragma unroll
    for (int r = 0; r < 4; r++) {
      int p = wave * 16 + quad * 4 + r;     // global query pos in window
      float qnp = qn[p];
      int cp = scode[p];
      float sv[4];
#pragma unroll
      for (int ni = 0; ni < 4; ni++) {
        int q = ni * 16 + lm;
        float dot = accS[ni][r];
        float denom = fmaxf(qnp * kn[q], 1e-6f);
        int dr = (p >> 3) - (q >> 3) + 7, dc = (p & 7) - (q & 7) + 7;
        float bv = tblh[dr * 15 + dc];
        bv = 16.f / (1.f + __expf(-bv));
        float mask = (cp == scode[q]) ? 0.f : -100.f;
        sv[ni] = dot / denom * scale + bv + mask;
      }
      float m = fmaxf(fmaxf(sv[0], sv[1]), fmaxf(sv[2], sv[3]));
#pragma unroll
      for (int off = 1; off < 16; off <<= 1) m = fmaxf(m, __shfl_xor(m, off, 64));
      float s = 0;
#pragma unroll
      for (int ni = 0; ni < 4; ni++) { sv[ni] = __expf(sv[ni] - m); s += sv[ni]; }
#pragma unroll
      for (int off = 1; off < 16; off <<= 1) s += __shfl_xor(s, off, 64);
      float inv = 1.f / s;
#pragma unroll
      for (int ni = 0; ni < 4; ni++)
        Pb[p * 72 + ni * 16 + lm] = f2bf(sv[ni] * inv);
    }
    // no barrier needed: PV's A-tile uses only this wave's own P strip (LDS same-wave RAW)

    // ---- PV: O strip = P(strip rows, 64 keys) x V(64 keys, 32 d) ----
    bf16x8 paf[2];
#pragma unroll
    for (int kc = 0; kc < 2; kc++)
      paf[kc] = *reinterpret_cast<const bf16x8*>(&Pb[(wave * 16 + lm) * 72 + kc * 32 + quad * 8]);
    f32x4 accO[2];
#pragma unroll
    for (int n2 = 0; n2 < 2; n2++) {
      f32x4 z = {0.f, 0.f, 0.f, 0.f};
#pragma unroll
      for (int kc = 0; kc < 2; kc++) {
        bf16x8 vb = *reinterpret_cast<const bf16x8*>(&VT[(n2 * 16 + lm) * 72 + kc * 32 + quad * 8]);
        z = __builtin_amdgcn_mfma_f32_16x16x32_bf16(paf[kc], vb, z, 0, 0, 0);
      }
      accO[n2] = z;
    }
#pragma unroll
    for (int n2 = 0; n2 < 2; n2++)
#pragma unroll
      for (int r = 0; r < 4; r++) {
        int p = wave * 16 + quad * 4 + r;
        Om[wbase + (size_t)p * 512 + h * 32 + n2 * 16 + lm] = f2bf(accO[n2][r]);
      }
    __syncthreads();   // before next head restages Qs/Ks/Pb
  }
}

// ---------- LN1: un-shift gather + layernorm + residual -> x1 bf16 ----------
__global__ __launch_bounds__(256) void ln1_kernel(
    const float* __restrict__ x, const unsigned short* __restrict__ proj,
    const float* __restrict__ g, const float* __restrict__ b,
    unsigned short* __restrict__ x1b)
{
  __shared__ float r1[4], r2[4], stats[2];
  int tkn = blockIdx.x;
  int bb = tkn >> 12, s = tkn & 4095;
  int h_ = s >> 6, w_ = s & 63;
  int r = (h_ + 60) & 63, cc = (w_ + 60) & 63;
  int wi = (r >> 3) * 8 + (cc >> 3);
  int p = (r & 7) * 8 + (cc & 7);
  size_t src = ((size_t)bb * 4096 + wi * 64 + p) * 512;
  int c = threadIdx.x * 2;
  unsigned int pv = *(const unsigned int*)&proj[src + c];
  float v0 = bf2f((unsigned short)(pv & 0xffff)), v1 = bf2f((unsigned short)(pv >> 16));
  float ls = v0 + v1, lq = v0 * v0 + v1 * v1;
  for (int off = 32; off > 0; off >>= 1) {
    ls += __shfl_down(ls, off, 64);
    lq += __shfl_down(lq, off, 64);
  }
  int wv = threadIdx.x >> 6, ln = threadIdx.x & 63;
  if (ln == 0) { r1[wv] = ls; r2[wv] = lq; }
  __syncthreads();
  if (threadIdx.x == 0) {
    float S1 = r1[0] + r1[1] + r1[2] + r1[3];
    float S2 = r2[0] + r2[1] + r2[2] + r2[3];
    float mean = S1 * (1.f / 512.f);
    float var = S2 * (1.f / 512.f) - mean * mean;
    stats[0] = mean; stats[1] = rsqrtf(var + 1e-6f);
  }
  __syncthreads();
  float mean = stats[0], rstd = stats[1];
  size_t o = (size_t)tkn * 512 + c;
  float2 xv = *(const float2*)&x[o];
  float y0 = (v0 - mean) * rstd * g[c] + b[c] + xv.x;
  float y1 = (v1 - mean) * rstd * g[c + 1] + b[c + 1] + xv.y;
  unsigned int ov = (unsigned int)f2bf(y0) | ((unsigned int)f2bf(y1) << 16);
  *(unsigned int*)&x1b[o] = ov;
}

// ---------- LN2 + residual -> out fp32 ----------
__global__ __launch_bounds__(256) void ln2_kernel(
    const unsigned short* __restrict__ x1b, const unsigned short* __restrict__ h2,
    const float* __restrict__ g, const float* __restrict__ b,
    float* __restrict__ out)
{
  __shared__ float r1[4], r2[4], stats[2];
  int tkn = blockIdx.x;
  int c = threadIdx.x * 2;
  size_t o = (size_t)tkn * 512 + c;
  unsigned int hv = *(const unsigned int*)&h2[o];
  float v0 = bf2f((unsigned short)(hv & 0xffff)), v1 = bf2f((unsigned short)(hv >> 16));
  float ls = v0 + v1, lq = v0 * v0 + v1 * v1;
  for (int off = 32; off > 0; off >>= 1) {
    ls += __shfl_down(ls, off, 64);
    lq += __shfl_down(lq, off, 64);
  }
  int wv = threadIdx.x >> 6, ln = threadIdx.x & 63;
  if (ln == 0) { r1[wv] = ls; r2[wv] = lq; }
  __syncthreads();
  if (threadIdx.x == 0) {
    float S1 = r1[0] + r1[1] + r1[2] + r1[3];
    float S2 = r2[0] + r2[1] + r2[2] + r2[3];
    float mean = S1 * (1.f / 512.f);
    float var = S2 * (1.f / 512.f) - mean * mean;
    stats[0] = mean; stats[1] = rsqrtf(var + 1e-6f);
  }
  __syncthreads();
  float mean = stats[0], rstd = stats[1];
  unsigned int xv = *(const unsigned int*)&x1b[o];
  float x0 = bf2f((unsigned short)(xv & 0xffff)), x1 = bf2f((unsigned short)(xv >> 16));
  float2 ov;
  ov.x = x0 + (v0 - mean) * rstd * g[c] + b[c];
  ov.y = x1 + (v1 - mean) * rstd * g[c + 1] + b[c + 1];
  *(float2*)&out[o] = ov;
}

// ---------- launcher ----------
extern "C" void kernel_launch(void* const* d_in, const int* in_sizes, int n_in,
                              void* d_out, int out_size, void* d_ws, size_t ws_size,
                              hipStream_t stream) {
  const float* x      = (const float*)d_in[0];
  const float* q_w    = (const float*)d_in[1];
  const float* q_b    = (const float*)d_in[2];
  const float* k_w    = (const float*)d_in[3];
  const float* v_w    = (const float*)d_in[4];
  const float* v_b    = (const float*)d_in[5];
  const float* proj_w = (const float*)d_in[6];
  const float* proj_b = (const float*)d_in[7];
  const float* tau    = (const float*)d_in[8];
  const float* cpb_w1 = (const float*)d_in[9];
  const float* cpb_b1 = (const float*)d_in[10];
  const float* cpb_w2 = (const float*)d_in[11];
  const float* cpb_b2 = (const float*)d_in[12];
  const float* n1g    = (const float*)d_in[13];
  const float* n1b    = (const float*)d_in[14];
  const float* n2g    = (const float*)d_in[15];
  const float* n2b    = (const float*)d_in[16];
  const float* mlp_w1 = (const float*)d_in[17];
  const float* mlp_b1 = (const float*)d_in[18];
  const float* mlp_w2 = (const float*)d_in[19];
  const float* mlp_b2 = (const float*)d_in[20];
  float* out = (float*)d_out;
  char* ws = (char*)d_ws;

  const size_t MB = 1048576;
  unsigned short* xw    = (unsigned short*)(ws + 0 * MB);
  unsigned short* Obuf  = (unsigned short*)(ws + 0 * MB);
  unsigned short* qbuf  = (unsigned short*)(ws + 64 * MB);
  unsigned short* projb = (unsigned short*)(ws + 64 * MB);
  unsigned short* kbuf  = (unsigned short*)(ws + 128 * MB);
  unsigned short* x1b   = (unsigned short*)(ws + 128 * MB);
  unsigned short* vbuf  = (unsigned short*)(ws + 192 * MB);
  unsigned short* h2b   = (unsigned short*)(ws + 192 * MB);
  unsigned short* hbuf  = (unsigned short*)(ws + 256 * MB);
  unsigned short* qwT = (unsigned short*)(ws + 320 * MB);
  unsigned short* kwT = (unsigned short*)(ws + 320 * MB + 524288);
  unsigned short* vwT = (unsigned short*)(ws + 320 * MB + 1048576);
  unsigned short* pwT = (unsigned short*)(ws + 320 * MB + 1572864);
  unsigned short* m1T = (unsigned short*)(ws + 320 * MB + 2097152);
  unsigned short* m2T = (unsigned short*)(ws + 320 * MB + 4194304);
  float* tbl          = (float*)         (ws + 320 * MB + 6291456);

  transpose_cast<<<dim3(16, 16), 256, 0, stream>>>(q_w,    qwT, 512, 512);
  transpose_cast<<<dim3(16, 16), 256, 0, stream>>>(k_w,    kwT, 512, 512);
  transpose_cast<<<dim3(16, 16), 256, 0, stream>>>(v_w,    vwT, 512, 512);
  transpose_cast<<<dim3(16, 16), 256, 0, stream>>>(proj_w, pwT, 512, 512);
  transpose_cast<<<dim3(64, 16), 256, 0, stream>>>(mlp_w1, m1T, 512, 2048);
  transpose_cast<<<dim3(16, 64), 256, 0, stream>>>(mlp_w2, m2T, 2048, 512);
  cpb_kernel<<<225, 512, 0, stream>>>(cpb_w1, cpb_b1, cpb_w2, cpb_b2, tbl);
  shift_part<<<32768, 256, 0, stream>>>(x, xw);
  gemm_bt<0><<<dim3(4, 512), 256, 0, stream>>>(xw, qwT, q_b,     qbuf, 65536, 512, 512);
  gemm_bt<0><<<dim3(4, 512), 256, 0, stream>>>(xw, kwT, nullptr, kbuf, 65536, 512, 512);
  gemm_bt<0><<<dim3(4, 512), 256, 0, stream>>>(xw, vwT, v_b,     vbuf, 65536, 512, 512);
  attn_mfma<<<1024, 256, 0, stream>>>(qbuf, kbuf, vbuf, tau, tbl, Obuf);
  gemm_bt<0><<<dim3(4, 512), 256, 0, stream>>>(Obuf, pwT, proj_b, projb, 65536, 512, 512);
  ln1_kernel<<<65536, 256, 0, stream>>>(x, projb, n1g, n1b, x1b);
  for (int c4 = 0; c4 < 4; c4++) {
    const unsigned short* a = x1b + (size_t)c4 * 16384 * 512;
    unsigned short* h2p = h2b + (size_t)c4 * 16384 * 512;
    gemm_bt<1><<<dim3(16, 128), 256, 0, stream>>>(a, m1T, mlp_b1, hbuf, 16384, 2048, 512);
    gemm_bt<0><<<dim3(4, 128), 256, 0, stream>>>(hbuf, m2T, mlp_b2, h2p, 16384, 512, 2048);
  }
  ln2_kernel<<<65536, 256, 0, stream>>>(x1b, h2b, n2g, n2b, out);
}